// Round 10
// baseline (345.543 us; speedup 1.0000x reference)
//
#include <hip/hip_runtime.h>
#include <math.h>

typedef unsigned char  uchar_t;
typedef unsigned int   uint32;
typedef __attribute__((ext_vector_type(2)))  int   i32x2;
typedef __attribute__((ext_vector_type(8)))  int   i32x8;
typedef __attribute__((ext_vector_type(16))) float f32x16;

#define EMB     512
#define NROWS   8192
#define NITEMS  4096
#define NSPLIT  16
#define CPS     512
#define CTILE   128
#define QTILE   128
#define NSTEPS  32
#define LDEPTH  8
#define KEEP    8
#define NRESC   16

// Proven form: LDS dest = base + lane*16, imm offset stays 0.
#define GLOAD_LDS(gp, lp) __builtin_amdgcn_global_load_lds( \
    (const __attribute__((address_space(1))) void*)(gp),    \
    (__attribute__((address_space(3))) void*)(lp), 16, 0, 0)

__device__ inline uint32 packkey(float v, int idx) {
    uint32 u = __float_as_uint(v);
    uint32 s = u ^ ((u & 0x80000000u) ? 0xFFFFFFFFu : 0x80000000u);
    return (s & 0xFFFFE000u) | ((uint32)idx ^ 0x1FFFu);
}

// ---------------- Phase A: fp64 norms + fp8 plane in word-pair-interleaved tiles ----
// Xq layout (R6, verified): 2KB block per (rowgroup g=row/32, kslab s=kbyte/64):
//   addr = (g*8 + s)*2048 + j8*256 + (row&31)*8 + b
__global__ void prep_kernel(const float* __restrict__ E,
                            uchar_t* __restrict__ Xq, double* __restrict__ invd) {
    const int row  = blockIdx.x * 4 + (threadIdx.x >> 6);
    const int lane = threadIdx.x & 63;
    const float4* p = (const float4*)(E + (size_t)row * EMB);
    float4 f0 = p[lane];
    float4 f1 = p[lane + 64];
    double s = (double)f0.x*f0.x + (double)f0.y*f0.y + (double)f0.z*f0.z + (double)f0.w*f0.w
             + (double)f1.x*f1.x + (double)f1.y*f1.y + (double)f1.z*f1.z + (double)f1.w*f1.w;
#pragma unroll
    for (int m = 32; m > 0; m >>= 1) s += __shfl_xor(s, m);
    const double inv = 1.0 / sqrt(s);
    if (lane == 0) invd[row] = inv;
    const float sc = (float)inv * 16.0f;
    int w0 = 0, w1 = 0;
    w0 = __builtin_amdgcn_cvt_pk_fp8_f32(f0.x * sc, f0.y * sc, w0, false);
    w0 = __builtin_amdgcn_cvt_pk_fp8_f32(f0.z * sc, f0.w * sc, w0, true);
    w1 = __builtin_amdgcn_cvt_pk_fp8_f32(f1.x * sc, f1.y * sc, w1, false);
    w1 = __builtin_amdgcn_cvt_pk_fp8_f32(f1.z * sc, f1.w * sc, w1, true);
    const int g  = row >> 5, l = row & 31;
    const int ks = lane >> 3, j8 = lane & 7;
    *(int2*)(Xq + ((size_t)(g * 8 + ks)) * 2048 + j8 * 256 + l * 8) = make_int2(w0, w1);
}

// ---------------- Phase B: dbuf MX-fp8 32x32x64 MFMA, 128x128 tile ----------------
// R10 PROBE: identical dataflow to verified R6/R9 sim, but grid DOUBLED
// (vb = blockIdx>>1): block pairs do byte-identical work and store identical
// key values to the same addresses (benign identical-value races; output
// unchanged). Purpose: sim's dur ~2x -> ranks above the 80us poison-fills in
// the top-5 counter display, recovering MfmaUtil/VALUBusy/Occupancy/
// LDS_BANK_CONFLICT for the first time since R2. Branch table for R11 is
// pre-committed in the journal. R9 (302us) remains the banked best.
__global__ __launch_bounds__(256, 4) void sim_topk_mfma(
    const uchar_t* __restrict__ Xq, uint32* __restrict__ keys_out) {

    __shared__ union {
        struct { uchar_t A[2][8192]; uchar_t B[2][8192]; } s;  // 32 KB dbuf staging
        struct { uint32 mk[128][37]; } m;                       // 18.9 KB merge
    } sh;

    const int t     = threadIdx.x;
    const int lane  = t & 63;
    const int wave  = t >> 6;
    const int wm    = wave >> 1;
    const int wn    = wave & 1;
    const int vb    = blockIdx.x >> 1;     // PROBE: two blocks per virtual tile
    const int rb    = vb >> 4;
    const int split = vb & 15;
    const int qbase = rb * QTILE;
    const int l31   = lane & 31;
    const int l5    = lane >> 5;

    const bool isA = (wave < 2);
    const int  wj  = wave & 1;
    const int  g0  = (isA ? split * CPS : qbase) >> 5;
    const uchar_t* cur[4];
#pragma unroll
    for (int c = 0; c < 4; ++c) {
        const int g = g0 + wj * 2 + (c >> 1);
        cur[c] = Xq + ((size_t)g * 8) * 2048 + (c & 1) * 1024 + lane * 16;   // ks=0
    }
    const long incA_ct = (long)4 * 8 * 2048 - 7 * 2048;   // +51200
    const long incB_ct = -(long)(7 * 2048);               // -14336

    auto stage = [&](int buf) {
        uchar_t* bp = (isA ? sh.s.A[buf] : sh.s.B[buf]) + wj * 4096;
#pragma unroll
        for (int c = 0; c < 4; ++c) GLOAD_LDS(cur[c], bp + c * 1024);
    };

    uint32 tv[2][LDEPTH];
#pragma unroll
    for (int fc = 0; fc < 2; ++fc)
#pragma unroll
        for (int d = 0; d < LDEPTH; ++d) tv[fc][d] = 0u;

    f32x16 acc[2][2];
#pragma unroll
    for (int fr = 0; fr < 2; ++fr)
#pragma unroll
        for (int fc = 0; fc < 2; ++fc)
#pragma unroll
            for (int q = 0; q < 16; ++q) acc[fr][fc][q] = 0.f;

    stage(0);   // prologue: step 0

    const int fo = (l5 << 10) + (l31 << 3);

    union U8 { i32x8 v8; i32x2 q[4]; };

#pragma unroll 1
    for (int s = 0; s < NSTEPS; ++s) {
        const int buf = s & 1;

        __syncthreads();   // drains this step's DMA (issued one compute-phase ago)

        if (s + 1 < NSTEPS) {
            const bool newct = ((s + 1) & 7) == 0;
            const long d = isA ? (newct ? incA_ct : 2048)
                               : (newct ? incB_ct : 2048);
#pragma unroll
            for (int c = 0; c < 4; ++c) cur[c] += d;
            stage((s + 1) & 1);
        }

        U8 a0, a1, b0, b1;
        {
            const uchar_t* Ab = sh.s.A[buf] + (wm * 4096) + fo;
            const uchar_t* Bb = sh.s.B[buf] + (wn * 4096) + fo;
#pragma unroll
            for (int jj = 0; jj < 4; ++jj) {
                a0.q[jj] = *(const i32x2*)(Ab + jj * 256);
                a1.q[jj] = *(const i32x2*)(Ab + 2048 + jj * 256);
                b0.q[jj] = *(const i32x2*)(Bb + jj * 256);
                b1.q[jj] = *(const i32x2*)(Bb + 2048 + jj * 256);
            }
        }

        acc[0][0] = __builtin_amdgcn_mfma_scale_f32_32x32x64_f8f6f4(
            a0.v8, b0.v8, acc[0][0], 0, 0, 0, 0x7F7F7F7F, 0, 0x7F7F7F7F);
        acc[1][0] = __builtin_amdgcn_mfma_scale_f32_32x32x64_f8f6f4(
            a1.v8, b0.v8, acc[1][0], 0, 0, 0, 0x7F7F7F7F, 0, 0x7F7F7F7F);
        acc[0][1] = __builtin_amdgcn_mfma_scale_f32_32x32x64_f8f6f4(
            a0.v8, b1.v8, acc[0][1], 0, 0, 0, 0x7F7F7F7F, 0, 0x7F7F7F7F);
        acc[1][1] = __builtin_amdgcn_mfma_scale_f32_32x32x64_f8f6f4(
            a1.v8, b1.v8, acc[1][1], 0, 0, 0, 0x7F7F7F7F, 0, 0x7F7F7F7F);

        if ((s & 7) == 7) {
            const int cand0 = split * CPS + (s >> 3) * CTILE;
#pragma unroll
            for (int fc = 0; fc < 2; ++fc) {
#pragma unroll
                for (int fr = 0; fr < 2; ++fr) {
                    float t0 = fmaxf(fmaxf(acc[fr][fc][0],  acc[fr][fc][1]),  acc[fr][fc][2]);
                    float t1 = fmaxf(fmaxf(acc[fr][fc][3],  acc[fr][fc][4]),  acc[fr][fc][5]);
                    float t2 = fmaxf(fmaxf(acc[fr][fc][6],  acc[fr][fc][7]),  acc[fr][fc][8]);
                    float t3 = fmaxf(fmaxf(acc[fr][fc][9],  acc[fr][fc][10]), acc[fr][fc][11]);
                    float t4 = fmaxf(fmaxf(acc[fr][fc][12], acc[fr][fc][13]), acc[fr][fc][14]);
                    float mx = fmaxf(fmaxf(fmaxf(t0, t1), t2),
                                     fmaxf(fmaxf(t3, t4), acc[fr][fc][15]));
                    if (packkey(mx, 0) > tv[fc][LDEPTH - 1]) {
                        const int jb = cand0 + wm * 64 + fr * 32 + (l5 << 2);
#pragma unroll
                        for (int reg = 0; reg < 16; ++reg) {
                            const int ci = jb + (reg & 3) + ((reg >> 2) << 3);
                            uint32 key = packkey(acc[fr][fc][reg], ci);
                            if (key > tv[fc][LDEPTH - 1]) {
                                uint32 c2 = key;
#pragma unroll
                                for (int d = 0; d < LDEPTH; ++d) {
                                    const uint32 a  = tv[fc][d];
                                    const uint32 hi = a > c2 ? a : c2;
                                    c2              = a > c2 ? c2 : a;
                                    tv[fc][d] = hi;
                                }
                            }
                        }
                    }
#pragma unroll
                    for (int q = 0; q < 16; ++q) acc[fr][fc][q] = 0.f;
                }
            }
        }
    }

    // ---- merge 4 lane-lists per query, emit sorted top-8 keys ----
    __syncthreads();
#pragma unroll
    for (int fc = 0; fc < 2; ++fc) {
        const int col = wn * 64 + fc * 32 + l31;
        const int sl  = wm * 2 + l5;
#pragma unroll
        for (int d = 0; d < LDEPTH; ++d) sh.m.mk[col][sl * 9 + d] = tv[fc][d];
        sh.m.mk[col][sl * 9 + 8] = 0u;   // sentinel
    }
    __syncthreads();
    if (t < 128) {
        int p[4] = {0, 0, 0, 0};
        const size_t base2 = ((size_t)(qbase + t) * NSPLIT + split) * KEEP;
#pragma unroll 1
        for (int sel = 0; sel < KEEP; ++sel) {
            uint32 bk = 0; int bl = 0;
#pragma unroll
            for (int l = 0; l < 4; ++l) {
                uint32 k = sh.m.mk[t][l * 9 + p[l]];
                if (k > bk) { bk = k; bl = l; }
            }
#pragma unroll
            for (int l = 0; l < 4; ++l) p[l] += (bl == l);
            keys_out[base2 + sel] = bk;
        }
    }
}

// ---------------- Phase C: TWO rows per block — rank-select top-16 + fp64 rescue ----
__global__ __launch_bounds__(256) void rescue_kernel(
    const float* __restrict__ E, const double* __restrict__ invd,
    const uint32* __restrict__ keys,
    const int* __restrict__ n_users, const int* __restrict__ n_entitys,
    const int* __restrict__ interactions, float* __restrict__ out) {

    __shared__ uint32 skeys[2][128];
    __shared__ float4 sq[2][128];
    __shared__ int    scand[2][NRESC];
    __shared__ double sd[2][NRESC];
    __shared__ int    sci[2][NRESC];
    __shared__ float  smemb[2][NRESC];
    __shared__ double contrib[2][8];

    const int t   = threadIdx.x;
    const int sub = t >> 7;          // 0/1 : which row of the pair
    const int tt  = t & 127;
    const int row = blockIdx.x * 2 + sub;

    skeys[sub][tt] = keys[(size_t)row * 128 + tt];
    sq[sub][tt]    = ((const float4*)(E + (size_t)row * EMB))[tt];
    if (tt < NRESC) scand[sub][tt] = 0;      // poison-proof
    if (tt < 8)     contrib[sub][tt] = 0.0;
    __syncthreads();

    {
        const uint32 k = skeys[sub][tt];
        int r = 0;
#pragma unroll 16
        for (int j = 0; j < 128; ++j) {
            const uint32 kj = skeys[sub][j];
            r += (kj > k) || (kj == k && j < tt);
        }
        if (r < NRESC) scand[sub][r] = (int)((k & 0x1FFFu) ^ 0x1FFFu);
    }
    __syncthreads();

    const int g    = tt >> 4;        // 0..7 : candidate-pair group within this row
    const int l16  = tt & 15;
    const int c0   = scand[sub][g] & (NROWS - 1);
    const int c1   = scand[sub][g + 8] & (NROWS - 1);
    const float4* C0 = (const float4*)(E + (size_t)c0 * EMB);
    const float4* C1 = (const float4*)(E + (size_t)c1 * EMB);
    double a0 = 0.0, a1 = 0.0;
#pragma unroll
    for (int j = 0; j < 8; ++j) {
        float4 q  = sq[sub][l16 + 16 * j];
        float4 v0 = C0[l16 + 16 * j];
        float4 v1 = C1[l16 + 16 * j];
        a0 += (double)q.x * v0.x + (double)q.y * v0.y
            + (double)q.z * v0.z + (double)q.w * v0.w;
        a1 += (double)q.x * v1.x + (double)q.y * v1.y
            + (double)q.z * v1.z + (double)q.w * v1.w;
    }
#pragma unroll
    for (int m = 8; m >= 1; m >>= 1) {
        a0 += __shfl_xor(a0, m, 16);
        a1 += __shfl_xor(a1, m, 16);
    }

    const int ent = n_entitys[row];
    if (l16 == 0) {
        const double ir = invd[row];
        sd[sub][g]     = a0 * ir * invd[c0];
        sd[sub][g + 8] = a1 * ir * invd[c1];
        sci[sub][g]     = c0;
        sci[sub][g + 8] = c1;
    }
    if (l16 == 1) {
        smemb[sub][g]     = (float)interactions[(size_t)n_users[c0] * NITEMS + ent];
        smemb[sub][g + 8] = (float)interactions[(size_t)n_users[c1] * NITEMS + ent];
    }
    __syncthreads();

    if (tt < NRESC) {
        const double v  = sd[sub][tt];
        const int    ci = sci[sub][tt];
        int r = 0;
#pragma unroll
        for (int j = 0; j < NRESC; ++j) {
            const double vj = sd[sub][j];
            const int    cj = sci[sub][j];
            r += (vj > v) || (vj == v && (cj < ci || (cj == ci && j < tt)));
        }
        if (r < 6) contrib[sub][r] = v * (double)smemb[sub][tt];
    }
    __syncthreads();
    if (tt == 0) {
        const double sum = contrib[sub][0] + contrib[sub][1] + contrib[sub][2]
                         + contrib[sub][3] + contrib[sub][4] + contrib[sub][5];
        out[row] = (float)(sum * (1.0 / 6.0));
    }
}

extern "C" void kernel_launch(void* const* d_in, const int* in_sizes, int n_in,
                              void* d_out, int out_size, void* d_ws, size_t ws_size,
                              hipStream_t stream) {
    const float* E            = (const float*)d_in[0];
    const int*   n_users      = (const int*)d_in[1];
    const int*   n_entitys    = (const int*)d_in[2];
    const int*   interactions = (const int*)d_in[3];
    float*       out          = (float*)d_out;

    uchar_t* Xq   = (uchar_t*)d_ws;
    double*  invd = (double*)(Xq + (size_t)NROWS * EMB);
    uint32*  keys = (uint32*)(invd + NROWS);

    prep_kernel<<<NROWS / 4, 256, 0, stream>>>(E, Xq, invd);
    // R10 PROBE: grid doubled (2x identical work, identical output) for counters
    sim_topk_mfma<<<(NROWS / QTILE) * NSPLIT * 2, 256, 0, stream>>>(Xq, keys);
    rescue_kernel<<<NROWS / 2, 256, 0, stream>>>(E, invd, keys, n_users, n_entitys,
                                                 interactions, out);
}

// Round 11
// 281.460 us; speedup vs baseline: 1.2277x; 1.2277x over previous
//
#include <hip/hip_runtime.h>
#include <math.h>

typedef unsigned char  uchar_t;
typedef unsigned int   uint32;
typedef __attribute__((ext_vector_type(2)))  int   i32x2;
typedef __attribute__((ext_vector_type(8)))  int   i32x8;
typedef __attribute__((ext_vector_type(16))) float f32x16;

#define EMB     512
#define NROWS   8192
#define NITEMS  4096
#define NSPLIT  16
#define CPS     512
#define CTILE   128
#define QTILE   128
#define NSTEPS  32
#define LDEPTH  6
#define KEEP    8
#define NRESC   16

// Proven form: LDS dest = base + lane*16, imm offset stays 0.
#define GLOAD_LDS(gp, lp) __builtin_amdgcn_global_load_lds( \
    (const __attribute__((address_space(1))) void*)(gp),    \
    (__attribute__((address_space(3))) void*)(lp), 16, 0, 0)

// Key contract (used by sim encode + rescue decode):
//   key = (bits(v + 512.0f) & 0xFFFFE000) | (8191 - ci)
// v = sim*256 in (-300,300) -> v+512 positive -> bits monotone in v.
// low13 = 8191 - ci = ci ^ 0x1FFF for 13-bit ci -> rescue decodes (k&0x1FFF)^0x1FFF.

// ---------------- Phase A: fp64 norms + fp8 plane in word-pair-interleaved tiles ----
// Xq layout (R6, verified): 2KB block per (rowgroup g=row/32, kslab s=kbyte/64):
//   addr = (g*8 + s)*2048 + j8*256 + (row&31)*8 + b
__global__ void prep_kernel(const float* __restrict__ E,
                            uchar_t* __restrict__ Xq, double* __restrict__ invd) {
    const int row  = blockIdx.x * 4 + (threadIdx.x >> 6);
    const int lane = threadIdx.x & 63;
    const float4* p = (const float4*)(E + (size_t)row * EMB);
    float4 f0 = p[lane];
    float4 f1 = p[lane + 64];
    double s = (double)f0.x*f0.x + (double)f0.y*f0.y + (double)f0.z*f0.z + (double)f0.w*f0.w
             + (double)f1.x*f1.x + (double)f1.y*f1.y + (double)f1.z*f1.z + (double)f1.w*f1.w;
#pragma unroll
    for (int m = 32; m > 0; m >>= 1) s += __shfl_xor(s, m);
    const double inv = 1.0 / sqrt(s);
    if (lane == 0) invd[row] = inv;
    const float sc = (float)inv * 16.0f;
    int w0 = 0, w1 = 0;
    w0 = __builtin_amdgcn_cvt_pk_fp8_f32(f0.x * sc, f0.y * sc, w0, false);
    w0 = __builtin_amdgcn_cvt_pk_fp8_f32(f0.z * sc, f0.w * sc, w0, true);
    w1 = __builtin_amdgcn_cvt_pk_fp8_f32(f1.x * sc, f1.y * sc, w1, false);
    w1 = __builtin_amdgcn_cvt_pk_fp8_f32(f1.z * sc, f1.w * sc, w1, true);
    const int g  = row >> 5, l = row & 31;
    const int ks = lane >> 3, j8 = lane & 7;
    *(int2*)(Xq + ((size_t)(g * 8 + ks)) * 2048 + j8 * 256 + l * 8) = make_int2(w0, w1);
}

// ---------------- Phase B: dbuf MX-fp8 32x32x64 MFMA, 128x128 tile ----------------
// R11: R6/R9 verified staging + slimmed epilogue. R10 probe showed VALUBusy 90%:
// SIMT analysis says per-value guards save nothing (P(any of 64 lanes accepts) ~ 1
// even at ct 3), so: guards + mx-tree DELETED (chains run unconditionally -- a
// too-small key bubbles off the end, correct), LDEPTH 8->6 (top-6-per-split exact;
// KEEP=8 tail is cushion; rescue re-ranks fp64), 3-op biased key per contract above.
// Per-subtile epilogue 378 -> 256 VALU ops. Probe grid reverted.
__global__ __launch_bounds__(256, 4) void sim_topk_mfma(
    const uchar_t* __restrict__ Xq, uint32* __restrict__ keys_out) {

    __shared__ union {
        struct { uchar_t A[2][8192]; uchar_t B[2][8192]; } s;  // 32 KB dbuf staging
        struct { uint32 mk[128][37]; } m;                       // 18.9 KB merge
    } sh;

    const int t     = threadIdx.x;
    const int lane  = t & 63;
    const int wave  = t >> 6;
    const int wm    = wave >> 1;
    const int wn    = wave & 1;
    const int rb    = blockIdx.x >> 4;
    const int split = blockIdx.x & 15;
    const int qbase = rb * QTILE;
    const int l31   = lane & 31;
    const int l5    = lane >> 5;

    const bool isA = (wave < 2);
    const int  wj  = wave & 1;
    const int  g0  = (isA ? split * CPS : qbase) >> 5;
    const uchar_t* cur[4];
#pragma unroll
    for (int c = 0; c < 4; ++c) {
        const int g = g0 + wj * 2 + (c >> 1);
        cur[c] = Xq + ((size_t)g * 8) * 2048 + (c & 1) * 1024 + lane * 16;   // ks=0
    }
    const long incA_ct = (long)4 * 8 * 2048 - 7 * 2048;   // +51200
    const long incB_ct = -(long)(7 * 2048);               // -14336

    auto stage = [&](int buf) {
        uchar_t* bp = (isA ? sh.s.A[buf] : sh.s.B[buf]) + wj * 4096;
#pragma unroll
        for (int c = 0; c < 4; ++c) GLOAD_LDS(cur[c], bp + c * 1024);
    };

    uint32 tv[2][LDEPTH];
#pragma unroll
    for (int fc = 0; fc < 2; ++fc)
#pragma unroll
        for (int d = 0; d < LDEPTH; ++d) tv[fc][d] = 0u;

    f32x16 acc[2][2];
#pragma unroll
    for (int fr = 0; fr < 2; ++fr)
#pragma unroll
        for (int fc = 0; fc < 2; ++fc)
#pragma unroll
            for (int q = 0; q < 16; ++q) acc[fr][fc][q] = 0.f;

    stage(0);   // prologue: step 0

    const int fo = (l5 << 10) + (l31 << 3);

    union U8 { i32x8 v8; i32x2 q[4]; };

#pragma unroll 1
    for (int s = 0; s < NSTEPS; ++s) {
        const int buf = s & 1;

        __syncthreads();   // drains this step's DMA (issued one compute-phase ago)

        if (s + 1 < NSTEPS) {
            const bool newct = ((s + 1) & 7) == 0;
            const long d = isA ? (newct ? incA_ct : 2048)
                               : (newct ? incB_ct : 2048);
#pragma unroll
            for (int c = 0; c < 4; ++c) cur[c] += d;
            stage((s + 1) & 1);
        }

        U8 a0, a1, b0, b1;
        {
            const uchar_t* Ab = sh.s.A[buf] + (wm * 4096) + fo;
            const uchar_t* Bb = sh.s.B[buf] + (wn * 4096) + fo;
#pragma unroll
            for (int jj = 0; jj < 4; ++jj) {
                a0.q[jj] = *(const i32x2*)(Ab + jj * 256);
                a1.q[jj] = *(const i32x2*)(Ab + 2048 + jj * 256);
                b0.q[jj] = *(const i32x2*)(Bb + jj * 256);
                b1.q[jj] = *(const i32x2*)(Bb + 2048 + jj * 256);
            }
        }

        acc[0][0] = __builtin_amdgcn_mfma_scale_f32_32x32x64_f8f6f4(
            a0.v8, b0.v8, acc[0][0], 0, 0, 0, 0x7F7F7F7F, 0, 0x7F7F7F7F);
        acc[1][0] = __builtin_amdgcn_mfma_scale_f32_32x32x64_f8f6f4(
            a1.v8, b0.v8, acc[1][0], 0, 0, 0, 0x7F7F7F7F, 0, 0x7F7F7F7F);
        acc[0][1] = __builtin_amdgcn_mfma_scale_f32_32x32x64_f8f6f4(
            a0.v8, b1.v8, acc[0][1], 0, 0, 0, 0x7F7F7F7F, 0, 0x7F7F7F7F);
        acc[1][1] = __builtin_amdgcn_mfma_scale_f32_32x32x64_f8f6f4(
            a1.v8, b1.v8, acc[1][1], 0, 0, 0, 0x7F7F7F7F, 0, 0x7F7F7F7F);

        if ((s & 7) == 7) {
            // ---- slim epilogue: 3-op biased key + unconditional 6-deep chain ----
            const int   cand0 = split * CPS + (s >> 3) * CTILE;
            const uint32 jt0  = 8191u - (uint32)(cand0 + wm * 64 + (l5 << 2));
#pragma unroll
            for (int fc = 0; fc < 2; ++fc) {
#pragma unroll
                for (int fr = 0; fr < 2; ++fr) {
                    const uint32 jt = jt0 - (uint32)(fr * 32);
#pragma unroll
                    for (int reg = 0; reg < 16; ++reg) {
                        const uint32 off = (uint32)((reg & 3) + ((reg >> 2) << 3));
                        uint32 c2 = (__float_as_uint(acc[fr][fc][reg] + 512.0f)
                                     & 0xFFFFE000u) | (jt - off);
#pragma unroll
                        for (int d = 0; d < LDEPTH; ++d) {
                            const uint32 a  = tv[fc][d];
                            const uint32 hi = a > c2 ? a : c2;   // v_max_u32
                            c2              = a > c2 ? c2 : a;   // v_min_u32
                            tv[fc][d] = hi;
                        }
                        acc[fr][fc][reg] = 0.f;
                    }
                }
            }
        }
    }

    // ---- merge 4 lane-lists per query, emit sorted top-8 keys ----
    __syncthreads();
#pragma unroll
    for (int fc = 0; fc < 2; ++fc) {
        const int col = wn * 64 + fc * 32 + l31;
        const int sl  = wm * 2 + l5;
#pragma unroll
        for (int d = 0; d < LDEPTH; ++d) sh.m.mk[col][sl * 9 + d] = tv[fc][d];
#pragma unroll
        for (int d = LDEPTH; d < 9; ++d) sh.m.mk[col][sl * 9 + d] = 0u;  // pads/sentinel
    }
    __syncthreads();
    if (t < 128) {
        int p[4] = {0, 0, 0, 0};
        const size_t base2 = ((size_t)(qbase + t) * NSPLIT + split) * KEEP;
#pragma unroll 1
        for (int sel = 0; sel < KEEP; ++sel) {
            uint32 bk = 0; int bl = 0;
#pragma unroll
            for (int l = 0; l < 4; ++l) {
                uint32 k = sh.m.mk[t][l * 9 + p[l]];
                if (k > bk) { bk = k; bl = l; }
            }
#pragma unroll
            for (int l = 0; l < 4; ++l) p[l] += (bl == l);
            keys_out[base2 + sel] = bk;
        }
    }
}

// ---------------- Phase C: TWO rows per block — rank-select top-16 + fp64 rescue ----
__global__ __launch_bounds__(256) void rescue_kernel(
    const float* __restrict__ E, const double* __restrict__ invd,
    const uint32* __restrict__ keys,
    const int* __restrict__ n_users, const int* __restrict__ n_entitys,
    const int* __restrict__ interactions, float* __restrict__ out) {

    __shared__ uint32 skeys[2][128];
    __shared__ float4 sq[2][128];
    __shared__ int    scand[2][NRESC];
    __shared__ double sd[2][NRESC];
    __shared__ int    sci[2][NRESC];
    __shared__ float  smemb[2][NRESC];
    __shared__ double contrib[2][8];

    const int t   = threadIdx.x;
    const int sub = t >> 7;          // 0/1 : which row of the pair
    const int tt  = t & 127;
    const int row = blockIdx.x * 2 + sub;

    skeys[sub][tt] = keys[(size_t)row * 128 + tt];
    sq[sub][tt]    = ((const float4*)(E + (size_t)row * EMB))[tt];
    if (tt < NRESC) scand[sub][tt] = 0;      // poison-proof
    if (tt < 8)     contrib[sub][tt] = 0.0;
    __syncthreads();

    {
        const uint32 k = skeys[sub][tt];
        int r = 0;
#pragma unroll 16
        for (int j = 0; j < 128; ++j) {
            const uint32 kj = skeys[sub][j];
            r += (kj > k) || (kj == k && j < tt);
        }
        if (r < NRESC) scand[sub][r] = (int)((k & 0x1FFFu) ^ 0x1FFFu);
    }
    __syncthreads();

    const int g    = tt >> 4;        // 0..7 : candidate-pair group within this row
    const int l16  = tt & 15;
    const int c0   = scand[sub][g] & (NROWS - 1);
    const int c1   = scand[sub][g + 8] & (NROWS - 1);
    const float4* C0 = (const float4*)(E + (size_t)c0 * EMB);
    const float4* C1 = (const float4*)(E + (size_t)c1 * EMB);
    double a0 = 0.0, a1 = 0.0;
#pragma unroll
    for (int j = 0; j < 8; ++j) {
        float4 q  = sq[sub][l16 + 16 * j];
        float4 v0 = C0[l16 + 16 * j];
        float4 v1 = C1[l16 + 16 * j];
        a0 += (double)q.x * v0.x + (double)q.y * v0.y
            + (double)q.z * v0.z + (double)q.w * v0.w;
        a1 += (double)q.x * v1.x + (double)q.y * v1.y
            + (double)q.z * v1.z + (double)q.w * v1.w;
    }
#pragma unroll
    for (int m = 8; m >= 1; m >>= 1) {
        a0 += __shfl_xor(a0, m, 16);
        a1 += __shfl_xor(a1, m, 16);
    }

    const int ent = n_entitys[row];
    if (l16 == 0) {
        const double ir = invd[row];
        sd[sub][g]     = a0 * ir * invd[c0];
        sd[sub][g + 8] = a1 * ir * invd[c1];
        sci[sub][g]     = c0;
        sci[sub][g + 8] = c1;
    }
    if (l16 == 1) {
        smemb[sub][g]     = (float)interactions[(size_t)n_users[c0] * NITEMS + ent];
        smemb[sub][g + 8] = (float)interactions[(size_t)n_users[c1] * NITEMS + ent];
    }
    __syncthreads();

    if (tt < NRESC) {
        const double v  = sd[sub][tt];
        const int    ci = sci[sub][tt];
        int r = 0;
#pragma unroll
        for (int j = 0; j < NRESC; ++j) {
            const double vj = sd[sub][j];
            const int    cj = sci[sub][j];
            r += (vj > v) || (vj == v && (cj < ci || (cj == ci && j < tt)));
        }
        if (r < 6) contrib[sub][r] = v * (double)smemb[sub][tt];
    }
    __syncthreads();
    if (tt == 0) {
        const double sum = contrib[sub][0] + contrib[sub][1] + contrib[sub][2]
                         + contrib[sub][3] + contrib[sub][4] + contrib[sub][5];
        out[row] = (float)(sum * (1.0 / 6.0));
    }
}

extern "C" void kernel_launch(void* const* d_in, const int* in_sizes, int n_in,
                              void* d_out, int out_size, void* d_ws, size_t ws_size,
                              hipStream_t stream) {
    const float* E            = (const float*)d_in[0];
    const int*   n_users      = (const int*)d_in[1];
    const int*   n_entitys    = (const int*)d_in[2];
    const int*   interactions = (const int*)d_in[3];
    float*       out          = (float*)d_out;

    uchar_t* Xq   = (uchar_t*)d_ws;
    double*  invd = (double*)(Xq + (size_t)NROWS * EMB);
    uint32*  keys = (uint32*)(invd + NROWS);

    prep_kernel<<<NROWS / 4, 256, 0, stream>>>(E, Xq, invd);
    sim_topk_mfma<<<(NROWS / QTILE) * NSPLIT, 256, 0, stream>>>(Xq, keys);
    rescue_kernel<<<NROWS / 2, 256, 0, stream>>>(E, invd, keys, n_users, n_entitys,
                                                 interactions, out);
}

// Round 12
// 273.229 us; speedup vs baseline: 1.2647x; 1.0301x over previous
//
#include <hip/hip_runtime.h>
#include <math.h>

typedef unsigned char  uchar_t;
typedef unsigned int   uint32;
typedef __attribute__((ext_vector_type(2)))  int   i32x2;
typedef __attribute__((ext_vector_type(8)))  int   i32x8;
typedef __attribute__((ext_vector_type(16))) float f32x16;

#define EMB     512
#define NROWS   8192
#define NITEMS  4096
#define NSPLIT  16
#define CPS     512
#define CTILE   128
#define QTILE   128
#define NSTEPS  32
#define LDEPTH  6
#define KEEP    8
#define NRESC   16

// Proven form: LDS dest = base + lane*16, imm offset stays 0.
#define GLOAD_LDS(gp, lp) __builtin_amdgcn_global_load_lds( \
    (const __attribute__((address_space(1))) void*)(gp),    \
    (__attribute__((address_space(3))) void*)(lp), 16, 0, 0)

// Key contract (sim encode + rescue decode):
//   key = (bits(v + 512.0f) & 0xFFFFE000) | (8191 - ci)
// v = sim*256 in (-300,300) -> v+512 positive -> bits monotone in v.
// low13 = 8191 - ci = ci ^ 0x1FFF for 13-bit ci -> rescue decodes (k&0x1FFF)^0x1FFF.

// Parallel sorted-insert step: one v_med3_u32 per slot (gfx9+ VOP3).
__device__ inline uint32 med3u(uint32 a, uint32 b, uint32 c) {
    uint32 d;
    asm("v_med3_u32 %0, %1, %2, %3" : "=v"(d) : "v"(a), "v"(b), "v"(c));
    return d;
}

// ---------------- Phase A: fp64 norms + fp8 plane in word-pair-interleaved tiles ----
// Xq layout (R6, verified): 2KB block per (rowgroup g=row/32, kslab s=kbyte/64):
//   addr = (g*8 + s)*2048 + j8*256 + (row&31)*8 + b
__global__ void prep_kernel(const float* __restrict__ E,
                            uchar_t* __restrict__ Xq, double* __restrict__ invd) {
    const int row  = blockIdx.x * 4 + (threadIdx.x >> 6);
    const int lane = threadIdx.x & 63;
    const float4* p = (const float4*)(E + (size_t)row * EMB);
    float4 f0 = p[lane];
    float4 f1 = p[lane + 64];
    double s = (double)f0.x*f0.x + (double)f0.y*f0.y + (double)f0.z*f0.z + (double)f0.w*f0.w
             + (double)f1.x*f1.x + (double)f1.y*f1.y + (double)f1.z*f1.z + (double)f1.w*f1.w;
#pragma unroll
    for (int m = 32; m > 0; m >>= 1) s += __shfl_xor(s, m);
    const double inv = 1.0 / sqrt(s);
    if (lane == 0) invd[row] = inv;
    const float sc = (float)inv * 16.0f;
    int w0 = 0, w1 = 0;
    w0 = __builtin_amdgcn_cvt_pk_fp8_f32(f0.x * sc, f0.y * sc, w0, false);
    w0 = __builtin_amdgcn_cvt_pk_fp8_f32(f0.z * sc, f0.w * sc, w0, true);
    w1 = __builtin_amdgcn_cvt_pk_fp8_f32(f1.x * sc, f1.y * sc, w1, false);
    w1 = __builtin_amdgcn_cvt_pk_fp8_f32(f1.z * sc, f1.w * sc, w1, true);
    const int g  = row >> 5, l = row & 31;
    const int ks = lane >> 3, j8 = lane & 7;
    *(int2*)(Xq + ((size_t)(g * 8 + ks)) * 2048 + j8 * 256 + l * 8) = make_int2(w0, w1);
}

// ---------------- Phase B: dbuf MX-fp8 32x32x64 MFMA, 128x128 tile ----------------
// R12 = banked R11 + med3 parallel insert. The 6-deep swap chain was 12 ops with a
// 12-level serial dependency per value; the med3 identity (tv'[0]=max(tv0,key),
// tv'[d]=med3(key, tv[d-1], tv[d])) is 6 ops with depth 1 -- each slot reads only
// OLD tv values. Per value 15 -> 9 ops; per epilogue 1024 -> 640; MFMA overlap up.
__global__ __launch_bounds__(256, 4) void sim_topk_mfma(
    const uchar_t* __restrict__ Xq, uint32* __restrict__ keys_out) {

    __shared__ union {
        struct { uchar_t A[2][8192]; uchar_t B[2][8192]; } s;  // 32 KB dbuf staging
        struct { uint32 mk[128][37]; } m;                       // 18.9 KB merge
    } sh;

    const int t     = threadIdx.x;
    const int lane  = t & 63;
    const int wave  = t >> 6;
    const int wm    = wave >> 1;
    const int wn    = wave & 1;
    const int rb    = blockIdx.x >> 4;
    const int split = blockIdx.x & 15;
    const int qbase = rb * QTILE;
    const int l31   = lane & 31;
    const int l5    = lane >> 5;

    const bool isA = (wave < 2);
    const int  wj  = wave & 1;
    const int  g0  = (isA ? split * CPS : qbase) >> 5;
    const uchar_t* cur[4];
#pragma unroll
    for (int c = 0; c < 4; ++c) {
        const int g = g0 + wj * 2 + (c >> 1);
        cur[c] = Xq + ((size_t)g * 8) * 2048 + (c & 1) * 1024 + lane * 16;   // ks=0
    }
    const long incA_ct = (long)4 * 8 * 2048 - 7 * 2048;   // +51200
    const long incB_ct = -(long)(7 * 2048);               // -14336

    auto stage = [&](int buf) {
        uchar_t* bp = (isA ? sh.s.A[buf] : sh.s.B[buf]) + wj * 4096;
#pragma unroll
        for (int c = 0; c < 4; ++c) GLOAD_LDS(cur[c], bp + c * 1024);
    };

    uint32 tv[2][LDEPTH];
#pragma unroll
    for (int fc = 0; fc < 2; ++fc)
#pragma unroll
        for (int d = 0; d < LDEPTH; ++d) tv[fc][d] = 0u;

    f32x16 acc[2][2];
#pragma unroll
    for (int fr = 0; fr < 2; ++fr)
#pragma unroll
        for (int fc = 0; fc < 2; ++fc)
#pragma unroll
            for (int q = 0; q < 16; ++q) acc[fr][fc][q] = 0.f;

    stage(0);   // prologue: step 0

    const int fo = (l5 << 10) + (l31 << 3);

    union U8 { i32x8 v8; i32x2 q[4]; };

#pragma unroll 1
    for (int s = 0; s < NSTEPS; ++s) {
        const int buf = s & 1;

        __syncthreads();   // drains this step's DMA (issued one compute-phase ago)

        if (s + 1 < NSTEPS) {
            const bool newct = ((s + 1) & 7) == 0;
            const long d = isA ? (newct ? incA_ct : 2048)
                               : (newct ? incB_ct : 2048);
#pragma unroll
            for (int c = 0; c < 4; ++c) cur[c] += d;
            stage((s + 1) & 1);
        }

        U8 a0, a1, b0, b1;
        {
            const uchar_t* Ab = sh.s.A[buf] + (wm * 4096) + fo;
            const uchar_t* Bb = sh.s.B[buf] + (wn * 4096) + fo;
#pragma unroll
            for (int jj = 0; jj < 4; ++jj) {
                a0.q[jj] = *(const i32x2*)(Ab + jj * 256);
                a1.q[jj] = *(const i32x2*)(Ab + 2048 + jj * 256);
                b0.q[jj] = *(const i32x2*)(Bb + jj * 256);
                b1.q[jj] = *(const i32x2*)(Bb + 2048 + jj * 256);
            }
        }

        acc[0][0] = __builtin_amdgcn_mfma_scale_f32_32x32x64_f8f6f4(
            a0.v8, b0.v8, acc[0][0], 0, 0, 0, 0x7F7F7F7F, 0, 0x7F7F7F7F);
        acc[1][0] = __builtin_amdgcn_mfma_scale_f32_32x32x64_f8f6f4(
            a1.v8, b0.v8, acc[1][0], 0, 0, 0, 0x7F7F7F7F, 0, 0x7F7F7F7F);
        acc[0][1] = __builtin_amdgcn_mfma_scale_f32_32x32x64_f8f6f4(
            a0.v8, b1.v8, acc[0][1], 0, 0, 0, 0x7F7F7F7F, 0, 0x7F7F7F7F);
        acc[1][1] = __builtin_amdgcn_mfma_scale_f32_32x32x64_f8f6f4(
            a1.v8, b1.v8, acc[1][1], 0, 0, 0, 0x7F7F7F7F, 0, 0x7F7F7F7F);

        if ((s & 7) == 7) {
            // ---- slim epilogue: 3-op biased key + med3 parallel 6-deep insert ----
            const int   cand0 = split * CPS + (s >> 3) * CTILE;
            const uint32 jt0  = 8191u - (uint32)(cand0 + wm * 64 + (l5 << 2));
#pragma unroll
            for (int fc = 0; fc < 2; ++fc) {
#pragma unroll
                for (int fr = 0; fr < 2; ++fr) {
                    const uint32 jt = jt0 - (uint32)(fr * 32);
#pragma unroll
                    for (int reg = 0; reg < 16; ++reg) {
                        const uint32 off = (uint32)((reg & 3) + ((reg >> 2) << 3));
                        const uint32 key = (__float_as_uint(acc[fr][fc][reg] + 512.0f)
                                            & 0xFFFFE000u) | (jt - off);
                        const uint32 n0 = tv[fc][0] > key ? tv[fc][0] : key;
                        tv[fc][5] = med3u(key, tv[fc][4], tv[fc][5]);
                        tv[fc][4] = med3u(key, tv[fc][3], tv[fc][4]);
                        tv[fc][3] = med3u(key, tv[fc][2], tv[fc][3]);
                        tv[fc][2] = med3u(key, tv[fc][1], tv[fc][2]);
                        tv[fc][1] = med3u(key, tv[fc][0], tv[fc][1]);
                        tv[fc][0] = n0;
                        acc[fr][fc][reg] = 0.f;
                    }
                }
            }
        }
    }

    // ---- merge 4 lane-lists per query, emit sorted top-8 keys ----
    __syncthreads();
#pragma unroll
    for (int fc = 0; fc < 2; ++fc) {
        const int col = wn * 64 + fc * 32 + l31;
        const int sl  = wm * 2 + l5;
#pragma unroll
        for (int d = 0; d < LDEPTH; ++d) sh.m.mk[col][sl * 9 + d] = tv[fc][d];
#pragma unroll
        for (int d = LDEPTH; d < 9; ++d) sh.m.mk[col][sl * 9 + d] = 0u;  // pads/sentinel
    }
    __syncthreads();
    if (t < 128) {
        int p[4] = {0, 0, 0, 0};
        const size_t base2 = ((size_t)(qbase + t) * NSPLIT + split) * KEEP;
#pragma unroll 1
        for (int sel = 0; sel < KEEP; ++sel) {
            uint32 bk = 0; int bl = 0;
#pragma unroll
            for (int l = 0; l < 4; ++l) {
                uint32 k = sh.m.mk[t][l * 9 + p[l]];
                if (k > bk) { bk = k; bl = l; }
            }
#pragma unroll
            for (int l = 0; l < 4; ++l) p[l] += (bl == l);
            keys_out[base2 + sel] = bk;
        }
    }
}

// ---------------- Phase C: TWO rows per block — rank-select top-16 + fp64 rescue ----
__global__ __launch_bounds__(256) void rescue_kernel(
    const float* __restrict__ E, const double* __restrict__ invd,
    const uint32* __restrict__ keys,
    const int* __restrict__ n_users, const int* __restrict__ n_entitys,
    const int* __restrict__ interactions, float* __restrict__ out) {

    __shared__ uint32 skeys[2][128];
    __shared__ float4 sq[2][128];
    __shared__ int    scand[2][NRESC];
    __shared__ double sd[2][NRESC];
    __shared__ int    sci[2][NRESC];
    __shared__ float  smemb[2][NRESC];
    __shared__ double contrib[2][8];

    const int t   = threadIdx.x;
    const int sub = t >> 7;          // 0/1 : which row of the pair
    const int tt  = t & 127;
    const int row = blockIdx.x * 2 + sub;

    skeys[sub][tt] = keys[(size_t)row * 128 + tt];
    sq[sub][tt]    = ((const float4*)(E + (size_t)row * EMB))[tt];
    if (tt < NRESC) scand[sub][tt] = 0;      // poison-proof
    if (tt < 8)     contrib[sub][tt] = 0.0;
    __syncthreads();

    {
        const uint32 k = skeys[sub][tt];
        int r = 0;
#pragma unroll 16
        for (int j = 0; j < 128; ++j) {
            const uint32 kj = skeys[sub][j];
            r += (kj > k) || (kj == k && j < tt);
        }
        if (r < NRESC) scand[sub][r] = (int)((k & 0x1FFFu) ^ 0x1FFFu);
    }
    __syncthreads();

    const int g    = tt >> 4;        // 0..7 : candidate-pair group within this row
    const int l16  = tt & 15;
    const int c0   = scand[sub][g] & (NROWS - 1);
    const int c1   = scand[sub][g + 8] & (NROWS - 1);
    const float4* C0 = (const float4*)(E + (size_t)c0 * EMB);
    const float4* C1 = (const float4*)(E + (size_t)c1 * EMB);
    double a0 = 0.0, a1 = 0.0;
#pragma unroll
    for (int j = 0; j < 8; ++j) {
        float4 q  = sq[sub][l16 + 16 * j];
        float4 v0 = C0[l16 + 16 * j];
        float4 v1 = C1[l16 + 16 * j];
        a0 += (double)q.x * v0.x + (double)q.y * v0.y
            + (double)q.z * v0.z + (double)q.w * v0.w;
        a1 += (double)q.x * v1.x + (double)q.y * v1.y
            + (double)q.z * v1.z + (double)q.w * v1.w;
    }
#pragma unroll
    for (int m = 8; m >= 1; m >>= 1) {
        a0 += __shfl_xor(a0, m, 16);
        a1 += __shfl_xor(a1, m, 16);
    }

    const int ent = n_entitys[row];
    if (l16 == 0) {
        const double ir = invd[row];
        sd[sub][g]     = a0 * ir * invd[c0];
        sd[sub][g + 8] = a1 * ir * invd[c1];
        sci[sub][g]     = c0;
        sci[sub][g + 8] = c1;
    }
    if (l16 == 1) {
        smemb[sub][g]     = (float)interactions[(size_t)n_users[c0] * NITEMS + ent];
        smemb[sub][g + 8] = (float)interactions[(size_t)n_users[c1] * NITEMS + ent];
    }
    __syncthreads();

    if (tt < NRESC) {
        const double v  = sd[sub][tt];
        const int    ci = sci[sub][tt];
        int r = 0;
#pragma unroll
        for (int j = 0; j < NRESC; ++j) {
            const double vj = sd[sub][j];
            const int    cj = sci[sub][j];
            r += (vj > v) || (vj == v && (cj < ci || (cj == ci && j < tt)));
        }
        if (r < 6) contrib[sub][r] = v * (double)smemb[sub][tt];
    }
    __syncthreads();
    if (tt == 0) {
        const double sum = contrib[sub][0] + contrib[sub][1] + contrib[sub][2]
                         + contrib[sub][3] + contrib[sub][4] + contrib[sub][5];
        out[row] = (float)(sum * (1.0 / 6.0));
    }
}

extern "C" void kernel_launch(void* const* d_in, const int* in_sizes, int n_in,
                              void* d_out, int out_size, void* d_ws, size_t ws_size,
                              hipStream_t stream) {
    const float* E            = (const float*)d_in[0];
    const int*   n_users      = (const int*)d_in[1];
    const int*   n_entitys    = (const int*)d_in[2];
    const int*   interactions = (const int*)d_in[3];
    float*       out          = (float*)d_out;

    uchar_t* Xq   = (uchar_t*)d_ws;
    double*  invd = (double*)(Xq + (size_t)NROWS * EMB);
    uint32*  keys = (uint32*)(invd + NROWS);

    prep_kernel<<<NROWS / 4, 256, 0, stream>>>(E, Xq, invd);
    sim_topk_mfma<<<(NROWS / QTILE) * NSPLIT, 256, 0, stream>>>(Xq, keys);
    rescue_kernel<<<NROWS / 2, 256, 0, stream>>>(E, invd, keys, n_users, n_entitys,
                                                 interactions, out);
}

// Round 13
// 270.293 us; speedup vs baseline: 1.2784x; 1.0109x over previous
//
#include <hip/hip_runtime.h>
#include <math.h>

typedef unsigned char  uchar_t;
typedef unsigned int   uint32;
typedef __attribute__((ext_vector_type(2)))  int   i32x2;
typedef __attribute__((ext_vector_type(8)))  int   i32x8;
typedef __attribute__((ext_vector_type(16))) float f32x16;

#define EMB     512
#define NROWS   8192
#define NITEMS  4096
#define NSPLIT  16
#define CPS     512
#define CTILE   128
#define QTILE   128
#define NSTEPS  32
#define LDEPTH  6
#define KEEP    8
#define NRESC   16

// Proven form: LDS dest = base + lane*16, imm offset stays 0.
#define GLOAD_LDS(gp, lp) __builtin_amdgcn_global_load_lds( \
    (const __attribute__((address_space(1))) void*)(gp),    \
    (__attribute__((address_space(3))) void*)(lp), 16, 0, 0)

// Key contract (sim encode + rescue decode):
//   key = (bits(v + 512.0f) & 0xFFFFE000) | (8191 - ci)
// v = sim*256 in (-300,300) -> v+512 positive -> bits monotone in v.
// low13 = 8191 - ci = ci ^ 0x1FFF for 13-bit ci -> rescue decodes (k&0x1FFF)^0x1FFF.

// Parallel sorted-insert step: one v_med3_u32 per slot (gfx9+ VOP3).
__device__ inline uint32 med3u(uint32 a, uint32 b, uint32 c) {
    uint32 d;
    asm("v_med3_u32 %0, %1, %2, %3" : "=v"(d) : "v"(a), "v"(b), "v"(c));
    return d;
}

// ---------------- Phase A: fp64 norms + fp8 plane in word-pair-interleaved tiles ----
// Xq layout (R6, verified): 2KB block per (rowgroup g=row/32, kslab s=kbyte/64):
//   addr = (g*8 + s)*2048 + j8*256 + (row&31)*8 + b
__global__ void prep_kernel(const float* __restrict__ E,
                            uchar_t* __restrict__ Xq, double* __restrict__ invd) {
    const int row  = blockIdx.x * 4 + (threadIdx.x >> 6);
    const int lane = threadIdx.x & 63;
    const float4* p = (const float4*)(E + (size_t)row * EMB);
    float4 f0 = p[lane];
    float4 f1 = p[lane + 64];
    double s = (double)f0.x*f0.x + (double)f0.y*f0.y + (double)f0.z*f0.z + (double)f0.w*f0.w
             + (double)f1.x*f1.x + (double)f1.y*f1.y + (double)f1.z*f1.z + (double)f1.w*f1.w;
#pragma unroll
    for (int m = 32; m > 0; m >>= 1) s += __shfl_xor(s, m);
    const double inv = 1.0 / sqrt(s);
    if (lane == 0) invd[row] = inv;
    const float sc = (float)inv * 16.0f;
    int w0 = 0, w1 = 0;
    w0 = __builtin_amdgcn_cvt_pk_fp8_f32(f0.x * sc, f0.y * sc, w0, false);
    w0 = __builtin_amdgcn_cvt_pk_fp8_f32(f0.z * sc, f0.w * sc, w0, true);
    w1 = __builtin_amdgcn_cvt_pk_fp8_f32(f1.x * sc, f1.y * sc, w1, false);
    w1 = __builtin_amdgcn_cvt_pk_fp8_f32(f1.z * sc, f1.w * sc, w1, true);
    const int g  = row >> 5, l = row & 31;
    const int ks = lane >> 3, j8 = lane & 7;
    *(int2*)(Xq + ((size_t)(g * 8 + ks)) * 2048 + j8 * 256 + l * 8) = make_int2(w0, w1);
}

// ---------------- Phase B: dbuf MX-fp8 32x32x64 MFMA, 128x128 tile ----------------
// R13: byte-identical to banked R12 (273us). Analysis this round rejected both sim
// restructures on evidence: counted-vmcnt port (guide m230: 2-phase already ~92% of
// 8-phase for this staging shape -> ~4us ceiling) and single-wave barrier-free
// (loses 4-wave operand sharing -> 1GB staging > L2 BW ceiling). Sim is frozen.
__global__ __launch_bounds__(256, 4) void sim_topk_mfma(
    const uchar_t* __restrict__ Xq, uint32* __restrict__ keys_out) {

    __shared__ union {
        struct { uchar_t A[2][8192]; uchar_t B[2][8192]; } s;  // 32 KB dbuf staging
        struct { uint32 mk[128][37]; } m;                       // 18.9 KB merge
    } sh;

    const int t     = threadIdx.x;
    const int lane  = t & 63;
    const int wave  = t >> 6;
    const int wm    = wave >> 1;
    const int wn    = wave & 1;
    const int rb    = blockIdx.x >> 4;
    const int split = blockIdx.x & 15;
    const int qbase = rb * QTILE;
    const int l31   = lane & 31;
    const int l5    = lane >> 5;

    const bool isA = (wave < 2);
    const int  wj  = wave & 1;
    const int  g0  = (isA ? split * CPS : qbase) >> 5;
    const uchar_t* cur[4];
#pragma unroll
    for (int c = 0; c < 4; ++c) {
        const int g = g0 + wj * 2 + (c >> 1);
        cur[c] = Xq + ((size_t)g * 8) * 2048 + (c & 1) * 1024 + lane * 16;   // ks=0
    }
    const long incA_ct = (long)4 * 8 * 2048 - 7 * 2048;   // +51200
    const long incB_ct = -(long)(7 * 2048);               // -14336

    auto stage = [&](int buf) {
        uchar_t* bp = (isA ? sh.s.A[buf] : sh.s.B[buf]) + wj * 4096;
#pragma unroll
        for (int c = 0; c < 4; ++c) GLOAD_LDS(cur[c], bp + c * 1024);
    };

    uint32 tv[2][LDEPTH];
#pragma unroll
    for (int fc = 0; fc < 2; ++fc)
#pragma unroll
        for (int d = 0; d < LDEPTH; ++d) tv[fc][d] = 0u;

    f32x16 acc[2][2];
#pragma unroll
    for (int fr = 0; fr < 2; ++fr)
#pragma unroll
        for (int fc = 0; fc < 2; ++fc)
#pragma unroll
            for (int q = 0; q < 16; ++q) acc[fr][fc][q] = 0.f;

    stage(0);   // prologue: step 0

    const int fo = (l5 << 10) + (l31 << 3);

    union U8 { i32x8 v8; i32x2 q[4]; };

#pragma unroll 1
    for (int s = 0; s < NSTEPS; ++s) {
        const int buf = s & 1;

        __syncthreads();   // drains this step's DMA (issued one compute-phase ago)

        if (s + 1 < NSTEPS) {
            const bool newct = ((s + 1) & 7) == 0;
            const long d = isA ? (newct ? incA_ct : 2048)
                               : (newct ? incB_ct : 2048);
#pragma unroll
            for (int c = 0; c < 4; ++c) cur[c] += d;
            stage((s + 1) & 1);
        }

        U8 a0, a1, b0, b1;
        {
            const uchar_t* Ab = sh.s.A[buf] + (wm * 4096) + fo;
            const uchar_t* Bb = sh.s.B[buf] + (wn * 4096) + fo;
#pragma unroll
            for (int jj = 0; jj < 4; ++jj) {
                a0.q[jj] = *(const i32x2*)(Ab + jj * 256);
                a1.q[jj] = *(const i32x2*)(Ab + 2048 + jj * 256);
                b0.q[jj] = *(const i32x2*)(Bb + jj * 256);
                b1.q[jj] = *(const i32x2*)(Bb + 2048 + jj * 256);
            }
        }

        acc[0][0] = __builtin_amdgcn_mfma_scale_f32_32x32x64_f8f6f4(
            a0.v8, b0.v8, acc[0][0], 0, 0, 0, 0x7F7F7F7F, 0, 0x7F7F7F7F);
        acc[1][0] = __builtin_amdgcn_mfma_scale_f32_32x32x64_f8f6f4(
            a1.v8, b0.v8, acc[1][0], 0, 0, 0, 0x7F7F7F7F, 0, 0x7F7F7F7F);
        acc[0][1] = __builtin_amdgcn_mfma_scale_f32_32x32x64_f8f6f4(
            a0.v8, b1.v8, acc[0][1], 0, 0, 0, 0x7F7F7F7F, 0, 0x7F7F7F7F);
        acc[1][1] = __builtin_amdgcn_mfma_scale_f32_32x32x64_f8f6f4(
            a1.v8, b1.v8, acc[1][1], 0, 0, 0, 0x7F7F7F7F, 0, 0x7F7F7F7F);

        if ((s & 7) == 7) {
            // ---- slim epilogue: 3-op biased key + med3 parallel 6-deep insert ----
            const int   cand0 = split * CPS + (s >> 3) * CTILE;
            const uint32 jt0  = 8191u - (uint32)(cand0 + wm * 64 + (l5 << 2));
#pragma unroll
            for (int fc = 0; fc < 2; ++fc) {
#pragma unroll
                for (int fr = 0; fr < 2; ++fr) {
                    const uint32 jt = jt0 - (uint32)(fr * 32);
#pragma unroll
                    for (int reg = 0; reg < 16; ++reg) {
                        const uint32 off = (uint32)((reg & 3) + ((reg >> 2) << 3));
                        const uint32 key = (__float_as_uint(acc[fr][fc][reg] + 512.0f)
                                            & 0xFFFFE000u) | (jt - off);
                        const uint32 n0 = tv[fc][0] > key ? tv[fc][0] : key;
                        tv[fc][5] = med3u(key, tv[fc][4], tv[fc][5]);
                        tv[fc][4] = med3u(key, tv[fc][3], tv[fc][4]);
                        tv[fc][3] = med3u(key, tv[fc][2], tv[fc][3]);
                        tv[fc][2] = med3u(key, tv[fc][1], tv[fc][2]);
                        tv[fc][1] = med3u(key, tv[fc][0], tv[fc][1]);
                        tv[fc][0] = n0;
                        acc[fr][fc][reg] = 0.f;
                    }
                }
            }
        }
    }

    // ---- merge 4 lane-lists per query, emit sorted top-8 keys ----
    __syncthreads();
#pragma unroll
    for (int fc = 0; fc < 2; ++fc) {
        const int col = wn * 64 + fc * 32 + l31;
        const int sl  = wm * 2 + l5;
#pragma unroll
        for (int d = 0; d < LDEPTH; ++d) sh.m.mk[col][sl * 9 + d] = tv[fc][d];
#pragma unroll
        for (int d = LDEPTH; d < 9; ++d) sh.m.mk[col][sl * 9 + d] = 0u;  // pads/sentinel
    }
    __syncthreads();
    if (t < 128) {
        int p[4] = {0, 0, 0, 0};
        const size_t base2 = ((size_t)(qbase + t) * NSPLIT + split) * KEEP;
#pragma unroll 1
        for (int sel = 0; sel < KEEP; ++sel) {
            uint32 bk = 0; int bl = 0;
#pragma unroll
            for (int l = 0; l < 4; ++l) {
                uint32 k = sh.m.mk[t][l * 9 + p[l]];
                if (k > bk) { bk = k; bl = l; }
            }
#pragma unroll
            for (int l = 0; l < 4; ++l) p[l] += (bl == l);
            keys_out[base2 + sel] = bk;
        }
    }
}

// ---------------- Phase C: FOUR rows per block — rank-select top-16 + fp64 rescue ----
// R13: grid 4096->2048. R9's re-blocking gained 15us from per-block fixed costs;
// halve them again. Per row: 64 threads; phase-1 scan covers 128 keys at 2/thread
// (reads halved); phase-2 = verified pair-dot pattern run twice (4 groups x 4 cands).
// All rank / tie-break / fp64 semantics identical to verified R9 rescue.
__global__ __launch_bounds__(256) void rescue_kernel(
    const float* __restrict__ E, const double* __restrict__ invd,
    const uint32* __restrict__ keys,
    const int* __restrict__ n_users, const int* __restrict__ n_entitys,
    const int* __restrict__ interactions, float* __restrict__ out) {

    __shared__ uint32 skeys[4][128];
    __shared__ float4 sq[4][128];
    __shared__ int    scand[4][NRESC];
    __shared__ double sd[4][NRESC];
    __shared__ int    sci[4][NRESC];
    __shared__ float  smemb[4][NRESC];
    __shared__ double contrib[4][8];

    const int t   = threadIdx.x;
    const int sub = t >> 6;          // 0..3 : which row of the quad
    const int tt  = t & 63;
    const int row = blockIdx.x * 4 + sub;

    skeys[sub][tt]      = keys[(size_t)row * 128 + tt];
    skeys[sub][tt + 64] = keys[(size_t)row * 128 + tt + 64];
    sq[sub][tt]      = ((const float4*)(E + (size_t)row * EMB))[tt];
    sq[sub][tt + 64] = ((const float4*)(E + (size_t)row * EMB))[tt + 64];
    if (tt < NRESC) scand[sub][tt] = 0;      // poison-proof
    if (tt < 8)     contrib[sub][tt] = 0.0;
    __syncthreads();

    {
        const uint32 ka = skeys[sub][tt];
        const uint32 kb = skeys[sub][tt + 64];
        int ra = 0, rb = 0;
#pragma unroll 16
        for (int j = 0; j < 128; ++j) {
            const uint32 kj = skeys[sub][j];
            ra += (kj > ka) || (kj == ka && j < tt);
            rb += (kj > kb) || (kj == kb && j < tt + 64);
        }
        if (ra < NRESC) scand[sub][ra] = (int)((ka & 0x1FFFu) ^ 0x1FFFu);
        if (rb < NRESC) scand[sub][rb] = (int)((kb & 0x1FFFu) ^ 0x1FFFu);
    }
    __syncthreads();

    const int g    = tt >> 4;        // 0..3 : candidate group within this row
    const int l16  = tt & 15;
    // two pair-dot passes: candidates (g, g+4) then (g+8, g+12)
#pragma unroll
    for (int pass = 0; pass < 2; ++pass) {
        const int i0 = g + pass * 8;
        const int i1 = g + pass * 8 + 4;
        const int c0 = scand[sub][i0] & (NROWS - 1);
        const int c1 = scand[sub][i1] & (NROWS - 1);
        const float4* C0 = (const float4*)(E + (size_t)c0 * EMB);
        const float4* C1 = (const float4*)(E + (size_t)c1 * EMB);
        double a0 = 0.0, a1 = 0.0;
#pragma unroll
        for (int j = 0; j < 8; ++j) {
            float4 q  = sq[sub][l16 + 16 * j];
            float4 v0 = C0[l16 + 16 * j];
            float4 v1 = C1[l16 + 16 * j];
            a0 += (double)q.x * v0.x + (double)q.y * v0.y
                + (double)q.z * v0.z + (double)q.w * v0.w;
            a1 += (double)q.x * v1.x + (double)q.y * v1.y
                + (double)q.z * v1.z + (double)q.w * v1.w;
        }
#pragma unroll
        for (int m = 8; m >= 1; m >>= 1) {
            a0 += __shfl_xor(a0, m, 16);
            a1 += __shfl_xor(a1, m, 16);
        }
        if (l16 == 0) {
            const double ir = invd[row];
            sd[sub][i0] = a0 * ir * invd[c0];
            sd[sub][i1] = a1 * ir * invd[c1];
            sci[sub][i0] = c0;
            sci[sub][i1] = c1;
        }
        if (l16 == 1) {
            const int ent = n_entitys[row];
            smemb[sub][i0] = (float)interactions[(size_t)n_users[c0] * NITEMS + ent];
            smemb[sub][i1] = (float)interactions[(size_t)n_users[c1] * NITEMS + ent];
        }
    }
    __syncthreads();

    if (tt < NRESC) {
        const double v  = sd[sub][tt];
        const int    ci = sci[sub][tt];
        int r = 0;
#pragma unroll
        for (int j = 0; j < NRESC; ++j) {
            const double vj = sd[sub][j];
            const int    cj = sci[sub][j];
            r += (vj > v) || (vj == v && (cj < ci || (cj == ci && j < tt)));
        }
        if (r < 6) contrib[sub][r] = v * (double)smemb[sub][tt];
    }
    __syncthreads();
    if (tt == 0) {
        const double sum = contrib[sub][0] + contrib[sub][1] + contrib[sub][2]
                         + contrib[sub][3] + contrib[sub][4] + contrib[sub][5];
        out[row] = (float)(sum * (1.0 / 6.0));
    }
}

extern "C" void kernel_launch(void* const* d_in, const int* in_sizes, int n_in,
                              void* d_out, int out_size, void* d_ws, size_t ws_size,
                              hipStream_t stream) {
    const float* E            = (const float*)d_in[0];
    const int*   n_users      = (const int*)d_in[1];
    const int*   n_entitys    = (const int*)d_in[2];
    const int*   interactions = (const int*)d_in[3];
    float*       out          = (float*)d_out;

    uchar_t* Xq   = (uchar_t*)d_ws;
    double*  invd = (double*)(Xq + (size_t)NROWS * EMB);
    uint32*  keys = (uint32*)(invd + NROWS);

    prep_kernel<<<NROWS / 4, 256, 0, stream>>>(E, Xq, invd);
    sim_topk_mfma<<<(NROWS / QTILE) * NSPLIT, 256, 0, stream>>>(Xq, keys);
    rescue_kernel<<<NROWS / 4, 256, 0, stream>>>(E, invd, keys, n_users, n_entitys,
                                                 interactions, out);
}